// Round 7
// baseline (267.244 us; speedup 1.0000x reference)
//
#include <hip/hip_runtime.h>

#define CIN    128
#define COUT   256
#define Hh     112
#define Ww     112
#define HW     12544          // 112*112
#define NBATCH 8
#define NPIX   (NBATCH*HW)    // 100352
#define KD     (CIN*9)        // 1152
#define PH     114            // padded H/W
#define PPIX   (NBATCH*PH*PH) // padded pixel count

typedef __bf16         v8bf __attribute__((ext_vector_type(8)));
typedef float          v4f  __attribute__((ext_vector_type(4)));

__device__ __forceinline__ unsigned short f2bf(float f) {
  unsigned int u = __float_as_uint(f);
  u += 0x7FFFu + ((u >> 16) & 1u);   // round-to-nearest-even
  return (unsigned short)(u >> 16);
}

__device__ __forceinline__ void gl_lds16(const void* g, void* l) {
  __builtin_amdgcn_global_load_lds(
      (const __attribute__((address_space(1))) void*)g,
      (__attribute__((address_space(3))) void*)l, 16, 0, 0);
}

// ---------------------------------------------------------------------------
// Kernel PRE: fused {channels-last bf16 transpose + per-pixel sum(x^2) +
// border zeroing + weight packing}. One block = one padded row (112 px x 128
// ch), float2-vectorized x loads. Proven config (R1/R2).
// ---------------------------------------------------------------------------
#define USS 130   // ushort-stride of LDS pixel row (128 + 2 pad)
__global__ __launch_bounds__(256) void k_pre(
    const float* __restrict__ x, const float* __restrict__ w,
    unsigned short* __restrict__ xbp, unsigned short* __restrict__ wpk,
    float* __restrict__ sq)
{
  __shared__ unsigned short US[112 * USS];   // 29,120 B
  __shared__ float sqp[112 * 4];

  int tid = threadIdx.x;
  int bid = blockIdx.x;

  if (bid >= NBATCH * PH) {
    int t = (bid - NBATCH * PH) * 2048 + tid * 8;
#pragma unroll
    for (int i = 0; i < 8; ++i) {
      int idx = t + i;
      int o  = idx / KD;
      int rr = idx - o * KD;
      int kk = rr >> 7;
      int c  = rr & 127;
      wpk[idx] = f2bf(w[(size_t)o * KD + c * 9 + kk]);
    }
    return;
  }

  int b  = bid / PH;
  int py = bid - b * PH;
  unsigned int* dstrow = (unsigned int*)xbp +
      (size_t)(b * PH + py) * PH * (CIN / 2);

  if (py == 0 || py == PH - 1) {
    uint4 z = {0, 0, 0, 0};
    for (int h = tid; h < PH * (CIN / 8); h += 256)
      *(uint4*)(dstrow + h * 4) = z;
    return;
  }

  int oy  = py - 1;
  int l   = tid & 63;
  int wid = tid >> 6;
  const float* xp = x + (size_t)b * CIN * HW + (size_t)oy * Ww;
  bool valid = l < 56;

  float a0 = 0.0f, a1 = 0.0f;
#pragma unroll
  for (int it = 0; it < 32; ++it) {
    int c = wid * 32 + it;
    float vx = 0.0f, vy = 0.0f;
    if (valid) {
      float2 v = *(const float2*)(xp + (size_t)c * HW + 2 * l);
      vx = v.x; vy = v.y;
    }
    a0 += vx * vx;
    a1 += vy * vy;
    if (valid) {
      US[(2 * l) * USS + c]     = f2bf(vx);
      US[(2 * l + 1) * USS + c] = f2bf(vy);
    }
  }
  if (valid) { sqp[(2 * l) * 4 + wid] = a0; sqp[(2 * l + 1) * 4 + wid] = a1; }
  __syncthreads();

  if (tid < 112) {
    float s = sqp[tid * 4] + sqp[tid * 4 + 1] + sqp[tid * 4 + 2] + sqp[tid * 4 + 3];
    sq[(size_t)b * HW + (size_t)oy * Ww + tid] = s;
  }

  unsigned int* dst = dstrow + (CIN / 2);
  for (int h = tid; h < 112 * 16; h += 256) {
    int px = h >> 4, part = h & 15;
    const unsigned short* s = &US[px * USS + part * 8];
    uint4 vv;
    vv.x = *(const unsigned int*)(s + 0);
    vv.y = *(const unsigned int*)(s + 2);
    vv.z = *(const unsigned int*)(s + 4);
    vv.w = *(const unsigned int*)(s + 6);
    *(uint4*)(dst + h * 4) = vv;
  }

  if (tid < 32) {
    uint4 z = {0, 0, 0, 0};
    int px   = (tid >> 4) ? (PH - 1) : 0;
    int part = tid & 15;
    *(uint4*)(dstrow + px * (CIN / 2) + part * 4) = z;
  }
}

// ---------------------------------------------------------------------------
// Kernel C: R6 structure (128x128 tile, BK=64, per-tap staging, epilogue
// invnorm, slab store). SINGLE CHANGE vs R6: LDS shrunk to 32,768 B by
// using a 32-row epilogue slab (4 passes instead of 2) -> 5 blocks/CU
// (5 x 32768 = 163840 = 160 KiB exactly) via __launch_bounds__(256, 5).
// Mechanism: still latency-bound (both pipes <32%); the 3->4 step gave
// -11%; the 5th resident block adds 25% more waves to overlap the
// per-K-step vmcnt(0)+barrier drain. K-loop byte-identical to R6.
// ---------------------------------------------------------------------------
#define SLAB_S 132   // fp32 slab stride: 16B-aligned rows, 2-way banks max
__global__ __launch_bounds__(256, 5) void k_conv(
    const unsigned short* __restrict__ wp,
    const unsigned short* __restrict__ xbp,
    const float* __restrict__ sq,
    const float* __restrict__ bias,
    float* __restrict__ out)
{
  __shared__ __align__(16) char smem[128 * 64 * 2 * 2];  // 32,768 B
  unsigned short* As = (unsigned short*)smem;            // [128][64]
  unsigned short* Bs = As + 128 * 64;                    // [128][64]
  float* slab = (float*)smem;                            // [32][SLAB_S] = 16,896 B

  int tid  = threadIdx.x;
  int lane = tid & 63;
  int wid  = tid >> 6;
  int wm   = wid >> 1, wn = wid & 1;
  int quad = lane >> 4;
  int l16  = lane & 15;

  // XCD-paired swizzle: both bm of one bn land on the same XCD (adjacent %8)
  int L  = blockIdx.x;           // 0..1567
  int g  = L >> 4;
  int j  = L & 15;
  int bn = g * 8 + (j & 7);      // 0..783
  int bm = j >> 3;               // 0..1

  // staging: thread -> (row = tid>>3 (+32/issue), chunk = (tid&7) XOR-swizzled)
  int srow = tid >> 3;
  int g16  = (tid & 7) ^ (srow & 7);

  const unsigned short* asrc = wp + (size_t)(bm * 128 + srow) * KD + g16 * 8;

  int pb[4];
#pragma unroll
  for (int jj = 0; jj < 4; ++jj) {
    int n  = bn * 128 + jj * 32 + srow;
    int b  = n / HW;  int r  = n - b * HW;
    int oy = r / Ww;  int ox = r - oy * Ww;
    pb[jj] = ((b * PH + oy) * PH + ox) * CIN + g16 * 8;
  }

  v4f acc[4][4];
#pragma unroll
  for (int mt = 0; mt < 4; ++mt)
#pragma unroll
    for (int nt = 0; nt < 4; ++nt)
#pragma unroll
      for (int q = 0; q < 4; ++q) acc[mt][nt][q] = 0.0f;

  const int khs[9] = {0,0,0,1,1,1,2,2,2};
  const int kws[9] = {0,1,2,0,1,2,0,1,2};

  for (int s = 0; s < 18; ++s) {
    int kk   = s >> 1;
    int c0   = (s & 1) * 64;
    int soff = (khs[kk] * PH + kws[kk]) * CIN + c0;

#pragma unroll
    for (int jj = 0; jj < 4; ++jj)
      gl_lds16(asrc + (size_t)jj * 32 * KD + s * 64,
               &As[(wid * 8 + jj * 32) * 64]);
#pragma unroll
    for (int jj = 0; jj < 4; ++jj)
      gl_lds16(xbp + pb[jj] + soff,
               &Bs[(wid * 8 + jj * 32) * 64]);

    __syncthreads();

#pragma unroll
    for (int h = 0; h < 2; ++h) {
      v8bf af[4], bfr[4];
      int cch = (h * 4 + quad) ^ (l16 & 7);
#pragma unroll
      for (int mt = 0; mt < 4; ++mt)
        af[mt] = *(const v8bf*)&As[(wm * 64 + mt * 16 + l16) * 64 + cch * 8];
#pragma unroll
      for (int nt = 0; nt < 4; ++nt)
        bfr[nt] = *(const v8bf*)&Bs[(wn * 64 + nt * 16 + l16) * 64 + cch * 8];
#pragma unroll
      for (int mt = 0; mt < 4; ++mt)
#pragma unroll
        for (int nt = 0; nt < 4; ++nt)
          acc[mt][nt] = __builtin_amdgcn_mfma_f32_16x16x32_bf16(
              af[mt], bfr[nt], acc[mt][nt], 0, 0, 0);
    }

    __syncthreads();
  }

  // ------------- epilogue -------------------------------------------------
  int nbase = bn * 128;

  // fused invnorm (epilogue placement, proven round 2)
  float invv[4];
#pragma unroll
  for (int nt = 0; nt < 4; ++nt) {
    int n  = nbase + wn * 64 + nt * 16 + l16;
    int b  = n / HW;  int r  = n - b * HW;
    int oy = r / Ww;  int ox = r - oy * Ww;
    const float* s = sq + (size_t)b * HW;
    float a2 = 0.0f;
#pragma unroll
    for (int dy = -1; dy <= 1; ++dy) {
      int iy = oy + dy;
      if (iy < 0 || iy >= Hh) continue;
#pragma unroll
      for (int dx = -1; dx <= 1; ++dx) {
        int ix = ox + dx;
        if (ix < 0 || ix >= Ww) continue;
        a2 += s[iy * Ww + ix];
      }
    }
    invv[nt] = 1.0f / fmaxf(sqrtf(a2), 1e-12f);
  }

  int bb = nbase / HW;           // 128 | HW, tile within one batch
  int rr = nbase - bb * HW;
  float* obase = out + (size_t)bb * COUT * HW + rr;

  // 4 passes of 32 output rows through the 32-row LDS slab
#pragma unroll
  for (int p = 0; p < 4; ++p) {
    if (p) __syncthreads();
    if (wm == (p >> 1)) {
      int mtb = (p & 1) * 2;     // this pass covers acc[mtb], acc[mtb+1]
#pragma unroll
      for (int m2 = 0; m2 < 2; ++m2)
#pragma unroll
        for (int nt = 0; nt < 4; ++nt) {
          int col = wn * 64 + nt * 16 + l16;
#pragma unroll
          for (int reg = 0; reg < 4; ++reg)
            slab[(m2 * 16 + quad * 4 + reg) * SLAB_S + col] =
                acc[mtb + m2][nt][reg] * invv[nt];
        }
    }
    __syncthreads();
    int row = tid >> 3;          // 0..31
    int o   = bm * 128 + p * 32 + row;
    float bv = bias[o];
    float* orow = obase + (size_t)o * HW;
#pragma unroll
    for (int k = 0; k < 4; ++k) {
      int c4 = ((tid & 7) + k * 8) * 4;
      v4f v = *(const v4f*)&slab[row * SLAB_S + c4];
      v4f r2;
#pragma unroll
      for (int q = 0; q < 4; ++q) r2[q] = v[q] + bv;
      *(v4f*)(orow + c4) = r2;   // 8 lanes -> 128B contiguous
    }
  }
}

// ---------------------------------------------------------------------------
extern "C" void kernel_launch(void* const* d_in, const int* in_sizes, int n_in,
                              void* d_out, int out_size, void* d_ws, size_t ws_size,
                              hipStream_t stream) {
  const float* x    = (const float*)d_in[0];  // [8,128,112,112]
  const float* w    = (const float*)d_in[1];  // [256,128,3,3]
  const float* bias = (const float*)d_in[2];  // [256]
  float* out        = (float*)d_out;          // [8,256,112,112]

  char* ws = (char*)d_ws;
  unsigned short* xbp = (unsigned short*)ws;                   // 26,615,808 B
  size_t off = (size_t)PPIX * CIN * 2;
  unsigned short* wpk = (unsigned short*)(ws + off);           // 589,824 B
  off += (size_t)COUT * KD * 2;
  float* sq = (float*)(ws + off);                              // 401,408 B

  k_pre<<<NBATCH * PH + (COUT * KD) / 2048, 256, 0, stream>>>(x, w, xbp, wpk, sq);
  k_conv<<<1568, 256, 0, stream>>>(wpk, xbp, sq, bias, out);
}

// Round 8
// 201.883 us; speedup vs baseline: 1.3238x; 1.3238x over previous
//
#include <hip/hip_runtime.h>

#define CIN    128
#define COUT   256
#define Hh     112
#define Ww     112
#define HW     12544          // 112*112
#define NBATCH 8
#define NPIX   (NBATCH*HW)    // 100352
#define KD     (CIN*9)        // 1152
#define PH     114            // padded H/W
#define PPIX   (NBATCH*PH*PH) // padded pixel count

typedef __bf16         v8bf __attribute__((ext_vector_type(8)));
typedef float          v4f  __attribute__((ext_vector_type(4)));

__device__ __forceinline__ unsigned short f2bf(float f) {
  unsigned int u = __float_as_uint(f);
  u += 0x7FFFu + ((u >> 16) & 1u);   // round-to-nearest-even
  return (unsigned short)(u >> 16);
}

__device__ __forceinline__ void gl_lds16(const void* g, void* l) {
  __builtin_amdgcn_global_load_lds(
      (const __attribute__((address_space(1))) void*)g,
      (__attribute__((address_space(3))) void*)l, 16, 0, 0);
}

// ---------------------------------------------------------------------------
// Kernel PRE: fused {channels-last bf16 transpose + per-pixel sum(x^2) +
// border zeroing + weight packing}. One block = one padded row (112 px x 128
// ch), float2-vectorized x loads. Proven config (R1/R2).
// ---------------------------------------------------------------------------
#define USS 130   // ushort-stride of LDS pixel row (128 + 2 pad)
__global__ __launch_bounds__(256) void k_pre(
    const float* __restrict__ x, const float* __restrict__ w,
    unsigned short* __restrict__ xbp, unsigned short* __restrict__ wpk,
    float* __restrict__ sq)
{
  __shared__ unsigned short US[112 * USS];   // 29,120 B
  __shared__ float sqp[112 * 4];

  int tid = threadIdx.x;
  int bid = blockIdx.x;

  if (bid >= NBATCH * PH) {
    int t = (bid - NBATCH * PH) * 2048 + tid * 8;
#pragma unroll
    for (int i = 0; i < 8; ++i) {
      int idx = t + i;
      int o  = idx / KD;
      int rr = idx - o * KD;
      int kk = rr >> 7;
      int c  = rr & 127;
      wpk[idx] = f2bf(w[(size_t)o * KD + c * 9 + kk]);
    }
    return;
  }

  int b  = bid / PH;
  int py = bid - b * PH;
  unsigned int* dstrow = (unsigned int*)xbp +
      (size_t)(b * PH + py) * PH * (CIN / 2);

  if (py == 0 || py == PH - 1) {
    uint4 z = {0, 0, 0, 0};
    for (int h = tid; h < PH * (CIN / 8); h += 256)
      *(uint4*)(dstrow + h * 4) = z;
    return;
  }

  int oy  = py - 1;
  int l   = tid & 63;
  int wid = tid >> 6;
  const float* xp = x + (size_t)b * CIN * HW + (size_t)oy * Ww;
  bool valid = l < 56;

  float a0 = 0.0f, a1 = 0.0f;
#pragma unroll
  for (int it = 0; it < 32; ++it) {
    int c = wid * 32 + it;
    float vx = 0.0f, vy = 0.0f;
    if (valid) {
      float2 v = *(const float2*)(xp + (size_t)c * HW + 2 * l);
      vx = v.x; vy = v.y;
    }
    a0 += vx * vx;
    a1 += vy * vy;
    if (valid) {
      US[(2 * l) * USS + c]     = f2bf(vx);
      US[(2 * l + 1) * USS + c] = f2bf(vy);
    }
  }
  if (valid) { sqp[(2 * l) * 4 + wid] = a0; sqp[(2 * l + 1) * 4 + wid] = a1; }
  __syncthreads();

  if (tid < 112) {
    float s = sqp[tid * 4] + sqp[tid * 4 + 1] + sqp[tid * 4 + 2] + sqp[tid * 4 + 3];
    sq[(size_t)b * HW + (size_t)oy * Ww + tid] = s;
  }

  unsigned int* dst = dstrow + (CIN / 2);
  for (int h = tid; h < 112 * 16; h += 256) {
    int px = h >> 4, part = h & 15;
    const unsigned short* s = &US[px * USS + part * 8];
    uint4 vv;
    vv.x = *(const unsigned int*)(s + 0);
    vv.y = *(const unsigned int*)(s + 2);
    vv.z = *(const unsigned int*)(s + 4);
    vv.w = *(const unsigned int*)(s + 6);
    *(uint4*)(dst + h * 4) = vv;
  }

  if (tid < 32) {
    uint4 z = {0, 0, 0, 0};
    int px   = (tid >> 4) ? (PH - 1) : 0;
    int part = tid & 15;
    *(uint4*)(dstrow + px * (CIN / 2) + part * 4) = z;
  }
}

// ---------------------------------------------------------------------------
// Kernel C: R6-exact structure (128x128 tile, BK=64, per-tap staging,
// epilogue invnorm, 64-row slab, __launch_bounds__(256,4) = 4 blocks/CU,
// VGPR 64, the proven 80.4us config). SINGLE CHANGE vs R6: chunked per-XCD
// block swizzle. 784 bn / 8 XCDs = 98 = HW/128, so XCD x (dispatch
// round-robin %8) gets EXACTLY batch image x: its xbp slice (3.33 MB) fits
// the 4 MB XCD L2 and is fetched from HBM once, reused across all 9 taps,
// both bm, and ~1.5 block generations. Old swizzle sent adjacent bn
// (shared 3x3 halo) to different XCDs -> 41 MB FETCH vs ~28 ideal.
// ---------------------------------------------------------------------------
#define SLAB_S 132   // fp32 slab stride: 16B-aligned rows, 2-way banks max
__global__ __launch_bounds__(256, 4) void k_conv(
    const unsigned short* __restrict__ wp,
    const unsigned short* __restrict__ xbp,
    const float* __restrict__ sq,
    const float* __restrict__ bias,
    float* __restrict__ out)
{
  __shared__ __align__(16) char smem[64 * SLAB_S * 4];   // 33,792 B
  unsigned short* As = (unsigned short*)smem;            // [128][64]
  unsigned short* Bs = As + 128 * 64;                    // [128][64]
  float* slab = (float*)smem;                            // [64][SLAB_S]

  int tid  = threadIdx.x;
  int lane = tid & 63;
  int wid  = tid >> 6;
  int wm   = wid >> 1, wn = wid & 1;
  int quad = lane >> 4;
  int l16  = lane & 15;

  // chunked per-XCD swizzle: XCD x owns batch image x (bn in [x*98,(x+1)*98)),
  // bm pairs adjacent in sequence. Bijective: x in [0,8), i>>1 in [0,98).
  int L  = blockIdx.x;           // 0..1567
  int xc = L & 7;                // XCD (hardware round-robin dispatch)
  int i  = L >> 3;               // per-XCD sequence 0..195
  int bm = i & 1;
  int bn = xc * 98 + (i >> 1);   // 0..783

  // staging: thread -> (row = tid>>3 (+32/issue), chunk = (tid&7) XOR-swizzled)
  int srow = tid >> 3;
  int g16  = (tid & 7) ^ (srow & 7);

  const unsigned short* asrc = wp + (size_t)(bm * 128 + srow) * KD + g16 * 8;

  int pb[4];
#pragma unroll
  for (int jj = 0; jj < 4; ++jj) {
    int n  = bn * 128 + jj * 32 + srow;
    int b  = n / HW;  int r  = n - b * HW;
    int oy = r / Ww;  int ox = r - oy * Ww;
    pb[jj] = ((b * PH + oy) * PH + ox) * CIN + g16 * 8;
  }

  v4f acc[4][4];
#pragma unroll
  for (int mt = 0; mt < 4; ++mt)
#pragma unroll
    for (int nt = 0; nt < 4; ++nt)
#pragma unroll
      for (int q = 0; q < 4; ++q) acc[mt][nt][q] = 0.0f;

  const int khs[9] = {0,0,0,1,1,1,2,2,2};
  const int kws[9] = {0,1,2,0,1,2,0,1,2};

  for (int s = 0; s < 18; ++s) {
    int kk   = s >> 1;
    int c0   = (s & 1) * 64;
    int soff = (khs[kk] * PH + kws[kk]) * CIN + c0;

#pragma unroll
    for (int jj = 0; jj < 4; ++jj)
      gl_lds16(asrc + (size_t)jj * 32 * KD + s * 64,
               &As[(wid * 8 + jj * 32) * 64]);
#pragma unroll
    for (int jj = 0; jj < 4; ++jj)
      gl_lds16(xbp + pb[jj] + soff,
               &Bs[(wid * 8 + jj * 32) * 64]);

    __syncthreads();

#pragma unroll
    for (int h = 0; h < 2; ++h) {
      v8bf af[4], bfr[4];
      int cch = (h * 4 + quad) ^ (l16 & 7);
#pragma unroll
      for (int mt = 0; mt < 4; ++mt)
        af[mt] = *(const v8bf*)&As[(wm * 64 + mt * 16 + l16) * 64 + cch * 8];
#pragma unroll
      for (int nt = 0; nt < 4; ++nt)
        bfr[nt] = *(const v8bf*)&Bs[(wn * 64 + nt * 16 + l16) * 64 + cch * 8];
#pragma unroll
      for (int mt = 0; mt < 4; ++mt)
#pragma unroll
        for (int nt = 0; nt < 4; ++nt)
          acc[mt][nt] = __builtin_amdgcn_mfma_f32_16x16x32_bf16(
              af[mt], bfr[nt], acc[mt][nt], 0, 0, 0);
    }

    __syncthreads();
  }

  // ------------- epilogue -------------------------------------------------
  int nbase = bn * 128;

  // fused invnorm (epilogue placement, proven round 2)
  float invv[4];
#pragma unroll
  for (int nt = 0; nt < 4; ++nt) {
    int n  = nbase + wn * 64 + nt * 16 + l16;
    int b  = n / HW;  int r  = n - b * HW;
    int oy = r / Ww;  int ox = r - oy * Ww;
    const float* s = sq + (size_t)b * HW;
    float a2 = 0.0f;
#pragma unroll
    for (int dy = -1; dy <= 1; ++dy) {
      int iy = oy + dy;
      if (iy < 0 || iy >= Hh) continue;
#pragma unroll
      for (int dx = -1; dx <= 1; ++dx) {
        int ix = ox + dx;
        if (ix < 0 || ix >= Ww) continue;
        a2 += s[iy * Ww + ix];
      }
    }
    invv[nt] = 1.0f / fmaxf(sqrtf(a2), 1e-12f);
  }

  int bb = nbase / HW;           // 128 | HW, tile within one batch
  int rr = nbase - bb * HW;
  float* obase = out + (size_t)bb * COUT * HW + rr;

  for (int pass = 0; pass < 2; ++pass) {
    if (pass) __syncthreads();
    if (wm == pass) {
#pragma unroll
      for (int mt = 0; mt < 4; ++mt)
#pragma unroll
        for (int nt = 0; nt < 4; ++nt) {
          int col = wn * 64 + nt * 16 + l16;
#pragma unroll
          for (int reg = 0; reg < 4; ++reg)
            slab[(mt * 16 + quad * 4 + reg) * SLAB_S + col] =
                acc[mt][nt][reg] * invv[nt];
        }
    }
    __syncthreads();
#pragma unroll
    for (int it = 0; it < 2; ++it) {
      int row = it * 32 + (tid >> 3);
      int o   = bm * 128 + pass * 64 + row;
      float bv = bias[o];
      float* orow = obase + (size_t)o * HW;
#pragma unroll
      for (int k = 0; k < 4; ++k) {
        int c4 = ((tid & 7) + k * 8) * 4;
        v4f v = *(const v4f*)&slab[row * SLAB_S + c4];
        v4f r2;
#pragma unroll
        for (int q = 0; q < 4; ++q) r2[q] = v[q] + bv;
        *(v4f*)(orow + c4) = r2;           // 8 lanes -> 128B contiguous
      }
    }
  }
}

// ---------------------------------------------------------------------------
extern "C" void kernel_launch(void* const* d_in, const int* in_sizes, int n_in,
                              void* d_out, int out_size, void* d_ws, size_t ws_size,
                              hipStream_t stream) {
  const float* x    = (const float*)d_in[0];  // [8,128,112,112]
  const float* w    = (const float*)d_in[1];  // [256,128,3,3]
  const float* bias = (const float*)d_in[2];  // [256]
  float* out        = (float*)d_out;          // [8,256,112,112]

  char* ws = (char*)d_ws;
  unsigned short* xbp = (unsigned short*)ws;                   // 26,615,808 B
  size_t off = (size_t)PPIX * CIN * 2;
  unsigned short* wpk = (unsigned short*)(ws + off);           // 589,824 B
  off += (size_t)COUT * KD * 2;
  float* sq = (float*)(ws + off);                              // 401,408 B

  k_pre<<<NBATCH * PH + (COUT * KD) / 2048, 256, 0, stream>>>(x, w, xbp, wpk, sq);
  k_conv<<<1568, 256, 0, stream>>>(wpk, xbp, sq, bias, out);
}